// Round 1
// 303.301 us; speedup vs baseline: 1.1028x; 1.1028x over previous
//
#include <hip/hip_runtime.h>

typedef float vfloat4 __attribute__((ext_vector_type(4)));
typedef float vfloat2 __attribute__((ext_vector_type(2)));

__device__ __forceinline__ int iclamp(int v, int lo, int hi) {
  return v < lo ? lo : (v > hi ? hi : v);
}

// Keys bicubic a=-0.5, jax.image.resize semantics: weights only (callers map
// taps to fixed f-row/col offsets). OOB taps dropped + renormalized.
__device__ __forceinline__ void taps4w(int i, int n, float inv, float w[4]) {
  float s = ((float)i + 0.5f) * inv - 0.5f;
  int k0 = (int)floorf(s);
  float sum = 0.f;
#pragma unroll
  for (int t = 0; t < 4; ++t) {
    int j = k0 - 1 + t;
    float d = fabsf(s - (float)j);
    float wt = (d <= 1.f) ? (((1.5f * d - 2.5f) * d) * d + 1.f)
                          : (((-0.5f * d + 2.5f) * d - 4.f) * d + 2.f);
    if (j < 0 || j >= n) wt = 0.f;
    w[t] = wt;
    sum += wt;
  }
  float r = 1.f / sum;
#pragma unroll
  for (int t = 0; t < 4; ++t) w[t] *= r;
}

// 4x interior phase weights (sample = 0.25*x - 0.375)
#define W0_0 (-0.0439453125f)
#define W0_1 ( 0.3896484375f)
#define W0_2 ( 0.7275390625f)
#define W0_3 (-0.0732421875f)
#define W1_0 (-0.0068359375f)
#define W1_1 ( 0.0908203125f)
#define W1_2 ( 0.9638671875f)
#define W1_3 (-0.0478515625f)
// 2x interior phase weights (sample = 0.5*x - 0.25)
#define U_0 (-0.0234375f)
#define U_1 ( 0.2265625f)
#define U_2 ( 0.8671875f)
#define U_3 (-0.0703125f)

// 2x2 outputs of bicubic 2x upsample for input cell (k,g), f = 5x5 patch
// (rows/cols k-2..k+2 / g-2..g+2, edge-clamped gather). Used by phases A/B
// (tiny work share); phases C/D use the sliding-window path below.
__device__ __forceinline__ void up2_cell(const float (&f)[5][5], int k, int g, int n,
                                         float (&o)[2][2]) {
  if (g >= 2 && g <= n - 3 && k >= 2 && k <= n - 3) {
    float v0[5], v1[5];
#pragma unroll
    for (int c = 0; c < 5; ++c) {
      v0[c] = U_0 * f[0][c] + U_1 * f[1][c] + U_2 * f[2][c] + U_3 * f[3][c];
      v1[c] = U_3 * f[1][c] + U_2 * f[2][c] + U_1 * f[3][c] + U_0 * f[4][c];
    }
    o[0][0] = U_0 * v0[0] + U_1 * v0[1] + U_2 * v0[2] + U_3 * v0[3];
    o[0][1] = U_3 * v0[1] + U_2 * v0[2] + U_1 * v0[3] + U_0 * v0[4];
    o[1][0] = U_0 * v1[0] + U_1 * v1[1] + U_2 * v1[2] + U_3 * v1[3];
    o[1][1] = U_3 * v1[1] + U_2 * v1[2] + U_1 * v1[3] + U_0 * v1[4];
  } else {
#pragma unroll
    for (int p = 0; p < 2; ++p) {
      float wy[4];
      taps4w(2 * k + p, n, 0.5f, wy);
      float vv[5];
#pragma unroll
      for (int c = 0; c < 5; ++c)
        vv[c] = wy[0] * f[p][c] + wy[1] * f[p + 1][c] + wy[2] * f[p + 2][c] + wy[3] * f[p + 3][c];
#pragma unroll
      for (int q = 0; q < 2; ++q) {
        float wx[4];
        taps4w(2 * g + q, n, 0.5f, wx);
        o[p][q] = wx[0] * vv[q] + wx[1] * vv[q + 1] + wx[2] * vv[q + 2] + wx[3] * vv[q + 3];
      }
    }
  }
}

// One block = one 32-row h256 slab of one image: builds h64/h128/h256 windows
// in LDS (all halos contained), then writes the 128x1024 output slab of the
// batch-flipped final 4x upsample with NT float4 stores.
//
// Phases C/D use column-run sliding windows: a thread owns a fixed column,
// walks consecutive k. Horizontal 4-tap applied FIRST into a 5-row register
// window hx[][]; each k-step then costs 5 LDS reads + (new-row horizontal) +
// vertical combine. Column weights/clamps are per-thread loop invariants
// (boundary columns resolved ONCE via taps4w -> no per-cell divergence);
// row weights are wave-uniform.
__global__ void __launch_bounds__(512, 4) fused_all(
    const float* __restrict__ cam256, const float* __restrict__ cam128,
    const float* __restrict__ cam64, const float* __restrict__ cam32,
    const float* __restrict__ w1, const float* __restrict__ b1,
    const float* __restrict__ w2, const float* __restrict__ b2,
    const float* __restrict__ w3, const float* __restrict__ b3,
    float* __restrict__ out) {
  __shared__ float s_h64[16 * 64];    //  4 KB
  __shared__ float s_h128[24 * 128];  // 12 KB
  __shared__ float s_h256[36 * 256];  // 36 KB

  const int tid = threadIdx.x;
  const int slab = blockIdx.x;  // 0..7
  const int b = blockIdx.y;     // 0..63
  const int s = slab * 32;      // h256 core rows [s, s+32)

  // Window row ranges (global coords). Each level covers the next level's
  // clamped 5-tap halo; verified max extents: h256 36 rows, h128 24, h64 16.
  const int r_lo = s - 2 < 0 ? 0 : s - 2, r_hi = s + 33 > 255 ? 255 : s + 33;
  const int kr0 = r_lo >> 1, kr1 = r_hi >> 1;
  const int h256_row0 = 2 * kr0;
  const int j_lo = kr0 - 2 < 0 ? 0 : kr0 - 2, j_hi = kr1 + 2 > 127 ? 127 : kr1 + 2;
  const int kj0 = j_lo >> 1, kj1 = j_hi >> 1;
  const int h128_row0 = 2 * kj0;
  const int m_lo = kj0 - 2 < 0 ? 0 : kj0 - 2, m_hi = kj1 + 2 > 63 ? 63 : kj1 + 2;
  const int km0 = m_lo >> 1, km1 = m_hi >> 1;
  const int h64_row0 = 2 * km0;

  const float w1_0 = w1[0], w1_1 = w1[1], b1_0 = b1[0];
  const float w2_0 = w2[0], w2_1 = w2[1], b2_0 = b2[0];
  const float w3_0 = w3[0], w3_1 = w3[1], b3_0 = b3[0];

  // ---- Phase A: h64 window from cam32 (global) + cam64 ----
  {
    const float* c32 = cam32 + (size_t)b * 32 * 32;
    const float* c64 = cam64 + (size_t)b * 64 * 64;
    const int nk = km1 - km0 + 1;
    for (int idx = tid; idx < nk * 32; idx += 512) {
      int k = km0 + (idx >> 5), g = idx & 31;
      float f[5][5];
#pragma unroll
      for (int i = 0; i < 5; ++i) {
        int r = iclamp(k - 2 + i, 0, 31);
#pragma unroll
        for (int c = 0; c < 5; ++c) f[i][c] = c32[r * 32 + iclamp(g - 2 + c, 0, 31)];
      }
      float o[2][2];
      up2_cell(f, k, g, 32, o);
#pragma unroll
      for (int p = 0; p < 2; ++p)
#pragma unroll
        for (int q = 0; q < 2; ++q) {
          int row = 2 * k + p, col = 2 * g + q;
          float h = w1_0 * o[p][q] + w1_1 * c64[row * 64 + col] + b1_0;
          s_h64[(row - h64_row0) * 64 + col] = fmaxf(h, 0.f);
        }
    }
  }
  __syncthreads();

  // ---- Phase B: h128 window from h64 (LDS) + cam128 ----
  {
    const float* c128 = cam128 + (size_t)b * 128 * 128;
    const int nk = kj1 - kj0 + 1;
    for (int idx = tid; idx < nk * 64; idx += 512) {
      int k = kj0 + (idx >> 6), g = idx & 63;
      float f[5][5];
#pragma unroll
      for (int i = 0; i < 5; ++i) {
        int r = iclamp(k - 2 + i, 0, 63) - h64_row0;
#pragma unroll
        for (int c = 0; c < 5; ++c) f[i][c] = s_h64[r * 64 + iclamp(g - 2 + c, 0, 63)];
      }
      float o[2][2];
      up2_cell(f, k, g, 64, o);
#pragma unroll
      for (int p = 0; p < 2; ++p)
#pragma unroll
        for (int q = 0; q < 2; ++q) {
          int row = 2 * k + p, col = 2 * g + q;
          float h = w2_0 * o[p][q] + w2_1 * c128[row * 128 + col] + b2_0;
          s_h128[(row - h128_row0) * 128 + col] = fmaxf(h, 0.f);
        }
    }
  }
  __syncthreads();

  // ---- Phase C: h256 window from h128 (LDS) + cam256, column-run ----
  // 4 row-chunks x 128 columns; thread owns one column, slides k.
  {
    const float* c256 = cam256 + (size_t)b * 256 * 256;
    const int gc = tid & 127;
    const int sub = tid >> 7;          // wave-uniform (128 | 64)
    const int nk = kr1 - kr0 + 1;      // 17..18
    const int len = (nk + 3) >> 2;
    const int ks = kr0 + sub * len;
    int ke = ks + len - 1;
    if (ke > kr1) ke = kr1;
    if (ks <= kr1) {
      const int cc0 = iclamp(gc - 2, 0, 127), cc1 = iclamp(gc - 1, 0, 127), cc2 = gc,
                cc3 = iclamp(gc + 1, 0, 127), cc4 = iclamp(gc + 2, 0, 127);
      // per-thread column weights (q=0 taps cols gc-2..gc+1; q=1 taps gc-1..gc+2)
      float wa0, wa1, wa2, wa3, wb0, wb1, wb2, wb3;
      if (gc >= 2 && gc <= 125) {
        wa0 = U_0; wa1 = U_1; wa2 = U_2; wa3 = U_3;
        wb0 = U_3; wb1 = U_2; wb2 = U_1; wb3 = U_0;
      } else {
        float ta[4], tb[4];
        taps4w(2 * gc, 128, 0.5f, ta);
        taps4w(2 * gc + 1, 128, 0.5f, tb);
        wa0 = ta[0]; wa1 = ta[1]; wa2 = ta[2]; wa3 = ta[3];
        wb0 = tb[0]; wb1 = tb[1]; wb2 = tb[2]; wb3 = tb[3];
      }
#define H128_ROW_HX(RCLAMP, DST)                                                \
      {                                                                         \
        const float* rp_ = s_h128 + ((RCLAMP) - h128_row0) * 128;               \
        float f0_ = rp_[cc0], f1_ = rp_[cc1], f2_ = rp_[cc2], f3_ = rp_[cc3],   \
              f4_ = rp_[cc4];                                                   \
        DST[0] = wa0 * f0_ + wa1 * f1_ + wa2 * f2_ + wa3 * f3_;                 \
        DST[1] = wb0 * f1_ + wb1 * f2_ + wb2 * f3_ + wb3 * f4_;                 \
      }
      float hx[5][2];  // rows k-2..k+2 (clamped), horizontally filtered
#pragma unroll
      for (int w = 0; w < 5; ++w) {
        int rc = iclamp(ks - 2 + w, 0, 127);
        H128_ROW_HX(rc, hx[w]);
      }
      for (int k = ks; k <= ke; ++k) {
        if (k > ks) {
#pragma unroll
          for (int w = 0; w < 4; ++w) { hx[w][0] = hx[w + 1][0]; hx[w][1] = hx[w + 1][1]; }
          int rc = iclamp(k + 2, 0, 127);
          H128_ROW_HX(rc, hx[4]);
        }
        // row weights (wave-uniform branch): p=0 over rows k-2..k+1, p=1 over k-1..k+2
        float p0w[4], p1w[4];
        if (k < 2 || k > 125) {
          taps4w(2 * k, 128, 0.5f, p0w);
          taps4w(2 * k + 1, 128, 0.5f, p1w);
        } else {
          p0w[0] = U_0; p0w[1] = U_1; p0w[2] = U_2; p0w[3] = U_3;
          p1w[0] = U_3; p1w[1] = U_2; p1w[2] = U_1; p1w[3] = U_0;
        }
        float o00 = p0w[0] * hx[0][0] + p0w[1] * hx[1][0] + p0w[2] * hx[2][0] + p0w[3] * hx[3][0];
        float o01 = p0w[0] * hx[0][1] + p0w[1] * hx[1][1] + p0w[2] * hx[2][1] + p0w[3] * hx[3][1];
        float o10 = p1w[0] * hx[1][0] + p1w[1] * hx[2][0] + p1w[2] * hx[3][0] + p1w[3] * hx[4][0];
        float o11 = p1w[0] * hx[1][1] + p1w[1] * hx[2][1] + p1w[2] * hx[3][1] + p1w[3] * hx[4][1];
        const int row0 = 2 * k, col = 2 * gc;
        vfloat2 ca = *(const vfloat2*)(c256 + (size_t)row0 * 256 + col);
        vfloat2 cb = *(const vfloat2*)(c256 + (size_t)(row0 + 1) * 256 + col);
        vfloat2 h0 = {fmaxf(w3_0 * o00 + w3_1 * ca.x + b3_0, 0.f),
                      fmaxf(w3_0 * o01 + w3_1 * ca.y + b3_0, 0.f)};
        vfloat2 h1 = {fmaxf(w3_0 * o10 + w3_1 * cb.x + b3_0, 0.f),
                      fmaxf(w3_0 * o11 + w3_1 * cb.y + b3_0, 0.f)};
        *(vfloat2*)(&s_h256[(row0 - h256_row0) * 256 + col]) = h0;
        *(vfloat2*)(&s_h256[(row0 + 1 - h256_row0) * 256 + col]) = h1;
      }
#undef H128_ROW_HX
    }
  }
  __syncthreads();

  // ---- Phase D: final 4x upsample of h256 slab, column-run, batch-flipped ----
  // thread: fixed column g, 16 consecutive k. Stores stay wave-contiguous 1KB.
  {
    float* outimg = out + (size_t)(63 - b) * 1024 * 1024;
    const int g = tid & 255;
    const int kbase = s + (tid >> 8) * 16;  // tid>>8 wave-uniform
    const int cc0 = iclamp(g - 2, 0, 255), cc1 = iclamp(g - 1, 0, 255), cc2 = g,
              cc3 = iclamp(g + 1, 0, 255), cc4 = iclamp(g + 2, 0, 255);
    // per-thread column weights; q=0,1 tap cols g-2..g+1, q=2,3 tap g-1..g+2
    float wx00, wx01, wx02, wx03, wx10, wx11, wx12, wx13;
    float wx20, wx21, wx22, wx23, wx30, wx31, wx32, wx33;
    if (g >= 2 && g <= 253) {
      wx00 = W0_0; wx01 = W0_1; wx02 = W0_2; wx03 = W0_3;
      wx10 = W1_0; wx11 = W1_1; wx12 = W1_2; wx13 = W1_3;
      wx20 = W1_3; wx21 = W1_2; wx22 = W1_1; wx23 = W1_0;
      wx30 = W0_3; wx31 = W0_2; wx32 = W0_1; wx33 = W0_0;
    } else {
      float t0[4], t1[4], t2[4], t3[4];
      taps4w(4 * g + 0, 256, 0.25f, t0);
      taps4w(4 * g + 1, 256, 0.25f, t1);
      taps4w(4 * g + 2, 256, 0.25f, t2);
      taps4w(4 * g + 3, 256, 0.25f, t3);
      wx00 = t0[0]; wx01 = t0[1]; wx02 = t0[2]; wx03 = t0[3];
      wx10 = t1[0]; wx11 = t1[1]; wx12 = t1[2]; wx13 = t1[3];
      wx20 = t2[0]; wx21 = t2[1]; wx22 = t2[2]; wx23 = t2[3];
      wx30 = t3[0]; wx31 = t3[1]; wx32 = t3[2]; wx33 = t3[3];
    }
#define H256_ROW_HX(RCLAMP, DST)                                                \
    {                                                                           \
      const float* rp_ = s_h256 + ((RCLAMP) - h256_row0) * 256;                 \
      float f0_ = rp_[cc0], f1_ = rp_[cc1], f2_ = rp_[cc2], f3_ = rp_[cc3],     \
            f4_ = rp_[cc4];                                                     \
      DST[0] = wx00 * f0_ + wx01 * f1_ + wx02 * f2_ + wx03 * f3_;               \
      DST[1] = wx10 * f0_ + wx11 * f1_ + wx12 * f2_ + wx13 * f3_;               \
      DST[2] = wx20 * f1_ + wx21 * f2_ + wx22 * f3_ + wx23 * f4_;               \
      DST[3] = wx30 * f1_ + wx31 * f2_ + wx32 * f3_ + wx33 * f4_;               \
    }
    float hx[5][4];  // rows k-2..k+2 (clamped), horizontally filtered
#pragma unroll
    for (int w = 0; w < 5; ++w) {
      int rc = iclamp(kbase - 2 + w, 0, 255);
      H256_ROW_HX(rc, hx[w]);
    }
    float* op = outimg + (size_t)4 * kbase * 1024 + 4 * g;
#pragma unroll
    for (int step = 0; step < 16; ++step) {
      const int k = kbase + step;
      if (step) {
#pragma unroll
        for (int w = 0; w < 4; ++w)
#pragma unroll
          for (int q = 0; q < 4; ++q) hx[w][q] = hx[w + 1][q];
        int rc = iclamp(k + 2, 0, 255);
        H256_ROW_HX(rc, hx[4]);
      }
      // row weights: only steps 0,1,14,15 can hit a boundary k (kbase is a
      // multiple of 16), so steps 2..13 fold to pure constants at compile time.
      float wy0[4], wy1[4], wy2[4], wy3[4];
      const bool maybe_bnd = (step < 2) || (step >= 14);
      if (maybe_bnd && (k < 2 || k > 253)) {
        taps4w(4 * k + 0, 256, 0.25f, wy0);
        taps4w(4 * k + 1, 256, 0.25f, wy1);
        taps4w(4 * k + 2, 256, 0.25f, wy2);
        taps4w(4 * k + 3, 256, 0.25f, wy3);
      } else {
        wy0[0] = W0_0; wy0[1] = W0_1; wy0[2] = W0_2; wy0[3] = W0_3;
        wy1[0] = W1_0; wy1[1] = W1_1; wy1[2] = W1_2; wy1[3] = W1_3;
        wy2[0] = W1_3; wy2[1] = W1_2; wy2[2] = W1_1; wy2[3] = W1_0;
        wy3[0] = W0_3; wy3[1] = W0_2; wy3[2] = W0_1; wy3[3] = W0_0;
      }
      vfloat4 v0, v1, v2, v3;
#pragma unroll
      for (int q = 0; q < 4; ++q) {
        v0[q] = wy0[0] * hx[0][q] + wy0[1] * hx[1][q] + wy0[2] * hx[2][q] + wy0[3] * hx[3][q];
        v1[q] = wy1[0] * hx[0][q] + wy1[1] * hx[1][q] + wy1[2] * hx[2][q] + wy1[3] * hx[3][q];
        v2[q] = wy2[0] * hx[1][q] + wy2[1] * hx[2][q] + wy2[2] * hx[3][q] + wy2[3] * hx[4][q];
        v3[q] = wy3[0] * hx[1][q] + wy3[1] * hx[2][q] + wy3[2] * hx[3][q] + wy3[3] * hx[4][q];
      }
      float* rp = op + (size_t)step * 4096;
      __builtin_nontemporal_store(v0, (vfloat4*)(rp));
      __builtin_nontemporal_store(v1, (vfloat4*)(rp + 1024));
      __builtin_nontemporal_store(v2, (vfloat4*)(rp + 2048));
      __builtin_nontemporal_store(v3, (vfloat4*)(rp + 3072));
    }
#undef H256_ROW_HX
  }
}

extern "C" void kernel_launch(void* const* d_in, const int* in_sizes, int n_in_,
                              void* d_out, int out_size, void* d_ws, size_t ws_size,
                              hipStream_t stream) {
  const float* cam256 = (const float*)d_in[0];
  const float* cam128 = (const float*)d_in[1];
  const float* cam64  = (const float*)d_in[2];
  const float* cam32  = (const float*)d_in[3];
  const float* w1 = (const float*)d_in[4];
  const float* b1 = (const float*)d_in[5];
  const float* w2 = (const float*)d_in[6];
  const float* b2 = (const float*)d_in[7];
  const float* w3 = (const float*)d_in[8];
  const float* b3 = (const float*)d_in[9];
  float* out = (float*)d_out;

  fused_all<<<dim3(8, 64), 512, 0, stream>>>(cam256, cam128, cam64, cam32,
                                             w1, b1, w2, b2, w3, b3, out);
}

// Round 2
// 295.965 us; speedup vs baseline: 1.1301x; 1.0248x over previous
//
#include <hip/hip_runtime.h>

typedef float vfloat4 __attribute__((ext_vector_type(4)));
typedef float vfloat2 __attribute__((ext_vector_type(2)));

template <bool B> struct BoolC { static constexpr bool value = B; };

__device__ __forceinline__ int iclamp(int v, int lo, int hi) {
  return v < lo ? lo : (v > hi ? hi : v);
}

// Keys bicubic a=-0.5, jax.image.resize semantics: weights only (callers map
// taps to fixed f-row/col offsets). OOB taps dropped + renormalized.
__device__ __forceinline__ void taps4w(int i, int n, float inv, float w[4]) {
  float s = ((float)i + 0.5f) * inv - 0.5f;
  int k0 = (int)floorf(s);
  float sum = 0.f;
#pragma unroll
  for (int t = 0; t < 4; ++t) {
    int j = k0 - 1 + t;
    float d = fabsf(s - (float)j);
    float wt = (d <= 1.f) ? (((1.5f * d - 2.5f) * d) * d + 1.f)
                          : (((-0.5f * d + 2.5f) * d - 4.f) * d + 2.f);
    if (j < 0 || j >= n) wt = 0.f;
    w[t] = wt;
    sum += wt;
  }
  float r = 1.f / sum;
#pragma unroll
  for (int t = 0; t < 4; ++t) w[t] *= r;
}

// 4x interior phase weights (sample = 0.25*x - 0.375)
#define W0_0 (-0.0439453125f)
#define W0_1 ( 0.3896484375f)
#define W0_2 ( 0.7275390625f)
#define W0_3 (-0.0732421875f)
#define W1_0 (-0.0068359375f)
#define W1_1 ( 0.0908203125f)
#define W1_2 ( 0.9638671875f)
#define W1_3 (-0.0478515625f)
// 2x interior phase weights (sample = 0.5*x - 0.25)
#define U_0 (-0.0234375f)
#define U_1 ( 0.2265625f)
#define U_2 ( 0.8671875f)
#define U_3 (-0.0703125f)

// 2x2 outputs of bicubic 2x upsample for input cell (k,g), f = 5x5 patch
// (rows/cols k-2..k+2 / g-2..g+2, edge-clamped gather). Used by phases A/B
// (tiny work share); phases C/D use sliding-window column runs.
__device__ __forceinline__ void up2_cell(const float (&f)[5][5], int k, int g, int n,
                                         float (&o)[2][2]) {
  if (g >= 2 && g <= n - 3 && k >= 2 && k <= n - 3) {
    float v0[5], v1[5];
#pragma unroll
    for (int c = 0; c < 5; ++c) {
      v0[c] = U_0 * f[0][c] + U_1 * f[1][c] + U_2 * f[2][c] + U_3 * f[3][c];
      v1[c] = U_3 * f[1][c] + U_2 * f[2][c] + U_1 * f[3][c] + U_0 * f[4][c];
    }
    o[0][0] = U_0 * v0[0] + U_1 * v0[1] + U_2 * v0[2] + U_3 * v0[3];
    o[0][1] = U_3 * v0[1] + U_2 * v0[2] + U_1 * v0[3] + U_0 * v0[4];
    o[1][0] = U_0 * v1[0] + U_1 * v1[1] + U_2 * v1[2] + U_3 * v1[3];
    o[1][1] = U_3 * v1[1] + U_2 * v1[2] + U_1 * v1[3] + U_0 * v1[4];
  } else {
#pragma unroll
    for (int p = 0; p < 2; ++p) {
      float wy[4];
      taps4w(2 * k + p, n, 0.5f, wy);
      float vv[5];
#pragma unroll
      for (int c = 0; c < 5; ++c)
        vv[c] = wy[0] * f[p][c] + wy[1] * f[p + 1][c] + wy[2] * f[p + 2][c] + wy[3] * f[p + 3][c];
#pragma unroll
      for (int q = 0; q < 2; ++q) {
        float wx[4];
        taps4w(2 * g + q, n, 0.5f, wx);
        o[p][q] = wx[0] * vv[q] + wx[1] * vv[q + 1] + wx[2] * vv[q + 2] + wx[3] * vv[q + 3];
      }
    }
  }
}

// One block = one 16-row h256 slab of one image (grid 16x64, 256 threads).
// LDS windows: h64 12 rows (3 KB), h128 16 rows (8 KB), h256 20 rows (20 KB)
// -> 31.75 KB -> 4 blocks/CU resident (vs 2 before): barrier/phase stalls of
// one block overlap with three others. Phase D is compile-time specialized:
// interior slabs (1..14) get a branch-free constant-weight body.
__global__ void __launch_bounds__(256, 4) fused_all(
    const float* __restrict__ cam256, const float* __restrict__ cam128,
    const float* __restrict__ cam64, const float* __restrict__ cam32,
    const float* __restrict__ w1, const float* __restrict__ b1,
    const float* __restrict__ w2, const float* __restrict__ b2,
    const float* __restrict__ w3, const float* __restrict__ b3,
    float* __restrict__ out) {
  __shared__ float s_h64[12 * 64];    //  3 KB
  __shared__ float s_h128[16 * 128];  //  8 KB
  __shared__ float s_h256[20 * 256];  // 20 KB

  const int tid = threadIdx.x;
  const int slab = blockIdx.x;  // 0..15
  const int b = blockIdx.y;     // 0..63
  const int s = slab * 16;      // h256 core rows [s, s+16)

  // Window row ranges (global coords). Each level covers the next level's
  // clamped 5-tap halo; max extents: h256 20 rows, h128 16, h64 12.
  const int r_lo = s - 2 < 0 ? 0 : s - 2, r_hi = s + 17 > 255 ? 255 : s + 17;
  const int kr0 = r_lo >> 1, kr1 = r_hi >> 1;
  const int h256_row0 = 2 * kr0;
  const int j_lo = kr0 - 2 < 0 ? 0 : kr0 - 2, j_hi = kr1 + 2 > 127 ? 127 : kr1 + 2;
  const int kj0 = j_lo >> 1, kj1 = j_hi >> 1;
  const int h128_row0 = 2 * kj0;
  const int m_lo = kj0 - 2 < 0 ? 0 : kj0 - 2, m_hi = kj1 + 2 > 63 ? 63 : kj1 + 2;
  const int km0 = m_lo >> 1, km1 = m_hi >> 1;
  const int h64_row0 = 2 * km0;

  const float w1_0 = w1[0], w1_1 = w1[1], b1_0 = b1[0];
  const float w2_0 = w2[0], w2_1 = w2[1], b2_0 = b2[0];
  const float w3_0 = w3[0], w3_1 = w3[1], b3_0 = b3[0];

  // ---- Phase A: h64 window from cam32 (global) + cam64 ----
  {
    const float* c32 = cam32 + (size_t)b * 32 * 32;
    const float* c64 = cam64 + (size_t)b * 64 * 64;
    const int nk = km1 - km0 + 1;  // <= 6
    for (int idx = tid; idx < nk * 32; idx += 256) {
      int k = km0 + (idx >> 5), g = idx & 31;
      float f[5][5];
#pragma unroll
      for (int i = 0; i < 5; ++i) {
        int r = iclamp(k - 2 + i, 0, 31);
#pragma unroll
        for (int c = 0; c < 5; ++c) f[i][c] = c32[r * 32 + iclamp(g - 2 + c, 0, 31)];
      }
      float o[2][2];
      up2_cell(f, k, g, 32, o);
#pragma unroll
      for (int p = 0; p < 2; ++p)
#pragma unroll
        for (int q = 0; q < 2; ++q) {
          int row = 2 * k + p, col = 2 * g + q;
          float h = w1_0 * o[p][q] + w1_1 * c64[row * 64 + col] + b1_0;
          s_h64[(row - h64_row0) * 64 + col] = fmaxf(h, 0.f);
        }
    }
  }
  __syncthreads();

  // ---- Phase B: h128 window from h64 (LDS) + cam128 ----
  {
    const float* c128 = cam128 + (size_t)b * 128 * 128;
    const int nk = kj1 - kj0 + 1;  // <= 8
    for (int idx = tid; idx < nk * 64; idx += 256) {
      int k = kj0 + (idx >> 6), g = idx & 63;
      float f[5][5];
#pragma unroll
      for (int i = 0; i < 5; ++i) {
        int r = iclamp(k - 2 + i, 0, 63) - h64_row0;
#pragma unroll
        for (int c = 0; c < 5; ++c) f[i][c] = s_h64[r * 64 + iclamp(g - 2 + c, 0, 63)];
      }
      float o[2][2];
      up2_cell(f, k, g, 64, o);
#pragma unroll
      for (int p = 0; p < 2; ++p)
#pragma unroll
        for (int q = 0; q < 2; ++q) {
          int row = 2 * k + p, col = 2 * g + q;
          float h = w2_0 * o[p][q] + w2_1 * c128[row * 128 + col] + b2_0;
          s_h128[(row - h128_row0) * 128 + col] = fmaxf(h, 0.f);
        }
    }
  }
  __syncthreads();

  // ---- Phase C: h256 window from h128 (LDS) + cam256, column-run ----
  // 2 row-chunks x 128 columns; thread owns one column, slides k.
  {
    const float* c256 = cam256 + (size_t)b * 256 * 256;
    const int gc = tid & 127;
    const int sub = tid >> 7;          // wave-uniform (0|1)
    const int nk = kr1 - kr0 + 1;      // 9..10
    const int len = (nk + 1) >> 1;
    const int ks = kr0 + sub * len;
    int ke = ks + len - 1;
    if (ke > kr1) ke = kr1;
    if (ks <= kr1) {
      const int cc0 = iclamp(gc - 2, 0, 127), cc1 = iclamp(gc - 1, 0, 127), cc2 = gc,
                cc3 = iclamp(gc + 1, 0, 127), cc4 = iclamp(gc + 2, 0, 127);
      float wa0, wa1, wa2, wa3, wb0, wb1, wb2, wb3;
      if (gc >= 2 && gc <= 125) {
        wa0 = U_0; wa1 = U_1; wa2 = U_2; wa3 = U_3;
        wb0 = U_3; wb1 = U_2; wb2 = U_1; wb3 = U_0;
      } else {
        float ta[4], tb[4];
        taps4w(2 * gc, 128, 0.5f, ta);
        taps4w(2 * gc + 1, 128, 0.5f, tb);
        wa0 = ta[0]; wa1 = ta[1]; wa2 = ta[2]; wa3 = ta[3];
        wb0 = tb[0]; wb1 = tb[1]; wb2 = tb[2]; wb3 = tb[3];
      }
#define H128_ROW_HX(RCLAMP, DST)                                                \
      {                                                                         \
        const float* rp_ = s_h128 + ((RCLAMP) - h128_row0) * 128;               \
        float f0_ = rp_[cc0], f1_ = rp_[cc1], f2_ = rp_[cc2], f3_ = rp_[cc3],   \
              f4_ = rp_[cc4];                                                   \
        DST[0] = wa0 * f0_ + wa1 * f1_ + wa2 * f2_ + wa3 * f3_;                 \
        DST[1] = wb0 * f1_ + wb1 * f2_ + wb2 * f3_ + wb3 * f4_;                 \
      }
      float hx[5][2];  // rows k-2..k+2 (clamped), horizontally filtered
#pragma unroll
      for (int w = 0; w < 5; ++w) {
        int rc = iclamp(ks - 2 + w, 0, 127);
        H128_ROW_HX(rc, hx[w]);
      }
      for (int k = ks; k <= ke; ++k) {
        if (k > ks) {
#pragma unroll
          for (int w = 0; w < 4; ++w) { hx[w][0] = hx[w + 1][0]; hx[w][1] = hx[w + 1][1]; }
          int rc = iclamp(k + 2, 0, 127);
          H128_ROW_HX(rc, hx[4]);
        }
        // row weights (wave-uniform branch)
        float p0w[4], p1w[4];
        if (k < 2 || k > 125) {
          taps4w(2 * k, 128, 0.5f, p0w);
          taps4w(2 * k + 1, 128, 0.5f, p1w);
        } else {
          p0w[0] = U_0; p0w[1] = U_1; p0w[2] = U_2; p0w[3] = U_3;
          p1w[0] = U_3; p1w[1] = U_2; p1w[2] = U_1; p1w[3] = U_0;
        }
        float o00 = p0w[0] * hx[0][0] + p0w[1] * hx[1][0] + p0w[2] * hx[2][0] + p0w[3] * hx[3][0];
        float o01 = p0w[0] * hx[0][1] + p0w[1] * hx[1][1] + p0w[2] * hx[2][1] + p0w[3] * hx[3][1];
        float o10 = p1w[0] * hx[1][0] + p1w[1] * hx[2][0] + p1w[2] * hx[3][0] + p1w[3] * hx[4][0];
        float o11 = p1w[0] * hx[1][1] + p1w[1] * hx[2][1] + p1w[2] * hx[3][1] + p1w[3] * hx[4][1];
        const int row0 = 2 * k, col = 2 * gc;
        vfloat2 ca = *(const vfloat2*)(c256 + (size_t)row0 * 256 + col);
        vfloat2 cb = *(const vfloat2*)(c256 + (size_t)(row0 + 1) * 256 + col);
        vfloat2 h0 = {fmaxf(w3_0 * o00 + w3_1 * ca.x + b3_0, 0.f),
                      fmaxf(w3_0 * o01 + w3_1 * ca.y + b3_0, 0.f)};
        vfloat2 h1 = {fmaxf(w3_0 * o10 + w3_1 * cb.x + b3_0, 0.f),
                      fmaxf(w3_0 * o11 + w3_1 * cb.y + b3_0, 0.f)};
        *(vfloat2*)(&s_h256[(row0 - h256_row0) * 256 + col]) = h0;
        *(vfloat2*)(&s_h256[(row0 + 1 - h256_row0) * 256 + col]) = h1;
      }
#undef H128_ROW_HX
    }
  }
  __syncthreads();

  // ---- Phase D: final 4x upsample of h256 slab, column-run, batch-flipped ----
  // thread: fixed column g = tid, 16 consecutive k. Plain cached vector
  // stores (wave-contiguous 1KB lines, same path the 6.4TB/s fill uses).
  {
    float* outimg = out + (size_t)(63 - b) * 1024 * 1024;
    const int g = tid;       // 0..255
    const int kbase = s;     // 16 rows
    const int cc0 = iclamp(g - 2, 0, 255), cc1 = iclamp(g - 1, 0, 255), cc2 = g,
              cc3 = iclamp(g + 1, 0, 255), cc4 = iclamp(g + 2, 0, 255);
    float wx00, wx01, wx02, wx03, wx10, wx11, wx12, wx13;
    float wx20, wx21, wx22, wx23, wx30, wx31, wx32, wx33;
    if (g >= 2 && g <= 253) {
      wx00 = W0_0; wx01 = W0_1; wx02 = W0_2; wx03 = W0_3;
      wx10 = W1_0; wx11 = W1_1; wx12 = W1_2; wx13 = W1_3;
      wx20 = W1_3; wx21 = W1_2; wx22 = W1_1; wx23 = W1_0;
      wx30 = W0_3; wx31 = W0_2; wx32 = W0_1; wx33 = W0_0;
    } else {
      float t0[4], t1[4], t2[4], t3[4];
      taps4w(4 * g + 0, 256, 0.25f, t0);
      taps4w(4 * g + 1, 256, 0.25f, t1);
      taps4w(4 * g + 2, 256, 0.25f, t2);
      taps4w(4 * g + 3, 256, 0.25f, t3);
      wx00 = t0[0]; wx01 = t0[1]; wx02 = t0[2]; wx03 = t0[3];
      wx10 = t1[0]; wx11 = t1[1]; wx12 = t1[2]; wx13 = t1[3];
      wx20 = t2[0]; wx21 = t2[1]; wx22 = t2[2]; wx23 = t2[3];
      wx30 = t3[0]; wx31 = t3[1]; wx32 = t3[2]; wx33 = t3[3];
    }
#define H256_ROW_HX(RCLAMP, DST)                                                \
    {                                                                           \
      const float* rp_ = s_h256 + ((RCLAMP) - h256_row0) * 256;                 \
      float f0_ = rp_[cc0], f1_ = rp_[cc1], f2_ = rp_[cc2], f3_ = rp_[cc3],     \
            f4_ = rp_[cc4];                                                     \
      DST[0] = wx00 * f0_ + wx01 * f1_ + wx02 * f2_ + wx03 * f3_;               \
      DST[1] = wx10 * f0_ + wx11 * f1_ + wx12 * f2_ + wx13 * f3_;               \
      DST[2] = wx20 * f1_ + wx21 * f2_ + wx22 * f3_ + wx23 * f4_;               \
      DST[3] = wx30 * f1_ + wx31 * f2_ + wx32 * f3_ + wx33 * f4_;               \
    }
    auto phaseD = [&](auto bndc) {
      constexpr bool BND = decltype(bndc)::value;
      float hx[5][4];  // rows k-2..k+2 (clamped), horizontally filtered
#pragma unroll
      for (int w = 0; w < 5; ++w) {
        int rc = iclamp(kbase - 2 + w, 0, 255);
        H256_ROW_HX(rc, hx[w]);
      }
      float* op = outimg + (size_t)4 * kbase * 1024 + 4 * g;
#pragma unroll
      for (int step = 0; step < 16; ++step) {
        const int k = kbase + step;
        if (step) {
#pragma unroll
          for (int w = 0; w < 4; ++w)
#pragma unroll
            for (int q = 0; q < 4; ++q) hx[w][q] = hx[w + 1][q];
          int rc = iclamp(k + 2, 0, 255);
          H256_ROW_HX(rc, hx[4]);
        }
        // Row weights: only boundary slabs (0,15) at steps 0,1,14,15 can hit a
        // boundary k; interior instantiation folds to pure constants.
        float wy0[4], wy1[4], wy2[4], wy3[4];
        const bool maybe_bnd = BND && ((step < 2) || (step >= 14));
        if (maybe_bnd && (k < 2 || k > 253)) {
          taps4w(4 * k + 0, 256, 0.25f, wy0);
          taps4w(4 * k + 1, 256, 0.25f, wy1);
          taps4w(4 * k + 2, 256, 0.25f, wy2);
          taps4w(4 * k + 3, 256, 0.25f, wy3);
        } else {
          wy0[0] = W0_0; wy0[1] = W0_1; wy0[2] = W0_2; wy0[3] = W0_3;
          wy1[0] = W1_0; wy1[1] = W1_1; wy1[2] = W1_2; wy1[3] = W1_3;
          wy2[0] = W1_3; wy2[1] = W1_2; wy2[2] = W1_1; wy2[3] = W1_0;
          wy3[0] = W0_3; wy3[1] = W0_2; wy3[2] = W0_1; wy3[3] = W0_0;
        }
        vfloat4 v0, v1, v2, v3;
#pragma unroll
        for (int q = 0; q < 4; ++q) {
          v0[q] = wy0[0] * hx[0][q] + wy0[1] * hx[1][q] + wy0[2] * hx[2][q] + wy0[3] * hx[3][q];
          v1[q] = wy1[0] * hx[0][q] + wy1[1] * hx[1][q] + wy1[2] * hx[2][q] + wy1[3] * hx[3][q];
          v2[q] = wy2[0] * hx[1][q] + wy2[1] * hx[2][q] + wy2[2] * hx[3][q] + wy2[3] * hx[4][q];
          v3[q] = wy3[0] * hx[1][q] + wy3[1] * hx[2][q] + wy3[2] * hx[3][q] + wy3[3] * hx[4][q];
        }
        float* rp = op + (size_t)step * 4096;
        *(vfloat4*)(rp) = v0;
        *(vfloat4*)(rp + 1024) = v1;
        *(vfloat4*)(rp + 2048) = v2;
        *(vfloat4*)(rp + 3072) = v3;
      }
    };
    if (slab == 0 || slab == 15) phaseD(BoolC<true>{});
    else phaseD(BoolC<false>{});
#undef H256_ROW_HX
  }
}

extern "C" void kernel_launch(void* const* d_in, const int* in_sizes, int n_in_,
                              void* d_out, int out_size, void* d_ws, size_t ws_size,
                              hipStream_t stream) {
  const float* cam256 = (const float*)d_in[0];
  const float* cam128 = (const float*)d_in[1];
  const float* cam64  = (const float*)d_in[2];
  const float* cam32  = (const float*)d_in[3];
  const float* w1 = (const float*)d_in[4];
  const float* b1 = (const float*)d_in[5];
  const float* w2 = (const float*)d_in[6];
  const float* b2 = (const float*)d_in[7];
  const float* w3 = (const float*)d_in[8];
  const float* b3 = (const float*)d_in[9];
  float* out = (float*)d_out;

  fused_all<<<dim3(16, 64), 256, 0, stream>>>(cam256, cam128, cam64, cam32,
                                              w1, b1, w2, b2, w3, b3, out);
}